// Round 1
// baseline (1767.501 us; speedup 1.0000x reference)
//
#include <hip/hip_runtime.h>

#define H 128
#define HC 64
#define NOUT 10
#define POOL_CHUNK 512

static constexpr int kN = 100000;
static constexpr int kE = 600000;
static constexpr int kG = 1000;

__device__ __forceinline__ float4 ld4(const float* p) { return *(const float4*)p; }
__device__ __forceinline__ void st4(float* p, float4 v) { *(float4*)p = v; }

// ---------------- edge aggregation on pos (C=2) ----------------
__global__ void k_edge_agg_pos(const int* __restrict__ src, const int* __restrict__ dst,
                               const float* __restrict__ pos, float* __restrict__ agg, int E) {
    int e = blockIdx.x * blockDim.x + threadIdx.x;
    if (e >= E) return;
    int s = src[e], d = dst[e];
    float2 p = ((const float2*)pos)[s];
    unsafeAtomicAdd(&agg[d * 2 + 0], p.x);
    unsafeAtomicAdd(&agg[d * 2 + 1], p.y);
}

// ---------------- pool pos into [G,2] ----------------
__global__ void k_pool_pos(const float* __restrict__ pos, const int* __restrict__ batch,
                           float* __restrict__ pp, int nN) {
    int i = blockIdx.x * blockDim.x + threadIdx.x;
    if (i >= nN) return;
    float2 p = ((const float2*)pos)[i];
    int b = batch[i];
    unsafeAtomicAdd(&pp[b * 2 + 0], p.x);
    unsafeAtomicAdd(&pp[b * 2 + 1], p.y);
}

// ---------------- first GIN1 linear: [N,2] -> [N,128], relu ----------------
__global__ void k_in2(const float* __restrict__ pos, const float* __restrict__ agg,
                      const float* __restrict__ W, const float* __restrict__ b,
                      float* __restrict__ out, int nN) {
    int idx = blockIdx.x * blockDim.x + threadIdx.x;  // node*32 + quad
    int i = idx >> 5, q = idx & 31;
    if (i >= nN) return;
    float2 p = ((const float2*)pos)[i];
    float2 a = ((const float2*)agg)[i];
    float x0 = p.x + a.x, x1 = p.y + a.y;
    float4 w0 = ld4(&W[q * 4]);
    float4 w1 = ld4(&W[H + q * 4]);
    float4 bb = ld4(&b[q * 4]);
    float4 r;
    r.x = fmaxf(x0 * w0.x + x1 * w1.x + bb.x, 0.f);
    r.y = fmaxf(x0 * w0.y + x1 * w1.y + bb.y, 0.f);
    r.z = fmaxf(x0 * w0.z + x1 * w1.z + bb.z, 0.f);
    r.w = fmaxf(x0 * w0.w + x1 * w1.w + bb.w, 0.f);
    st4(&out[(size_t)i * H + q * 4], r);
}

// ---------------- main matmul: OUT = [BN](relu((IN1[+IN2]) @ W + b)) ----------------
template <bool HAS_IN2, bool HAS_BN>
__global__ __launch_bounds__(256) void k_mm(
    const float* __restrict__ in1, const float* __restrict__ in2,
    const float* __restrict__ W, const float* __restrict__ bias,
    const float* __restrict__ bn_g, const float* __restrict__ bn_b,
    const float* __restrict__ bn_rm, const float* __restrict__ bn_rv,
    float* __restrict__ out, int nN) {
    __shared__ float Ws[H * H];      // 64 KB
    __shared__ float As[32 * H];     // 16 KB
    const int t = threadIdx.x;

    // stage W (128x128 f32)
#pragma unroll
    for (int r = 0; r < 16; ++r) {
        int idx = r * 1024 + t * 4;
        st4(&Ws[idx], ld4(&W[idx]));
    }

    const int kq = t & 31;
    const int f0 = kq * 4;
    const int ng4 = (t >> 5) * 4;
    const float4 b4 = ld4(&bias[f0]);

    float4 s4, sh4;
    if (HAS_BN) {
        float4 g = ld4(&bn_g[f0]);
        float4 be = ld4(&bn_b[f0]);
        float4 rm = ld4(&bn_rm[f0]);
        float4 rv = ld4(&bn_rv[f0]);
        s4.x = g.x * rsqrtf(rv.x + 1e-5f); s4.y = g.y * rsqrtf(rv.y + 1e-5f);
        s4.z = g.z * rsqrtf(rv.z + 1e-5f); s4.w = g.w * rsqrtf(rv.w + 1e-5f);
        sh4.x = be.x - rm.x * s4.x; sh4.y = be.y - rm.y * s4.y;
        sh4.z = be.z - rm.z * s4.z; sh4.w = be.w - rm.w * s4.w;
    }

    const int base = blockIdx.x * 128;
    for (int it = 0; it < 4; ++it) {
        const int n0 = base + it * 32;
        __syncthreads();
        // stage A tile: 32 rows x 128
#pragma unroll
        for (int r = 0; r < 4; ++r) {
            int idx = r * 1024 + t * 4;
            int row = idx >> 7, col = idx & 127;
            int node = n0 + row;
            float4 v = make_float4(0.f, 0.f, 0.f, 0.f);
            if (node < nN) {
                v = ld4(&in1[(size_t)node * H + col]);
                if (HAS_IN2) {
                    float4 u = ld4(&in2[(size_t)node * H + col]);
                    v.x += u.x; v.y += u.y; v.z += u.z; v.w += u.w;
                }
            }
            st4(&As[row * H + col], v);
        }
        __syncthreads();

        float4 acc[4] = {b4, b4, b4, b4};
#pragma unroll 8
        for (int j = 0; j < H; j += 4) {
            const float4 w0 = ld4(&Ws[(j + 0) * H + f0]);
            const float4 w1 = ld4(&Ws[(j + 1) * H + f0]);
            const float4 w2 = ld4(&Ws[(j + 2) * H + f0]);
            const float4 w3 = ld4(&Ws[(j + 3) * H + f0]);
#pragma unroll
            for (int n = 0; n < 4; ++n) {
                const float4 a = ld4(&As[(ng4 + n) * H + j]);
                acc[n].x += a.x * w0.x + a.y * w1.x + a.z * w2.x + a.w * w3.x;
                acc[n].y += a.x * w0.y + a.y * w1.y + a.z * w2.y + a.w * w3.y;
                acc[n].z += a.x * w0.z + a.y * w1.z + a.z * w2.z + a.w * w3.z;
                acc[n].w += a.x * w0.w + a.y * w1.w + a.z * w2.w + a.w * w3.w;
            }
        }

#pragma unroll
        for (int n = 0; n < 4; ++n) {
            const int node = n0 + ng4 + n;
            if (node < nN) {
                float4 v = acc[n];
                v.x = fmaxf(v.x, 0.f); v.y = fmaxf(v.y, 0.f);
                v.z = fmaxf(v.z, 0.f); v.w = fmaxf(v.w, 0.f);
                if (HAS_BN) {
                    v.x = v.x * s4.x + sh4.x; v.y = v.y * s4.y + sh4.y;
                    v.z = v.z * s4.z + sh4.z; v.w = v.w * s4.w + sh4.w;
                }
                st4(&out[(size_t)node * H + f0], v);
            }
        }
    }
}

// ---------------- edge aggregation on H=128 features ----------------
__global__ void k_edge_agg_h(const int* __restrict__ src, const int* __restrict__ dst,
                             const float* __restrict__ x, float* __restrict__ agg, int E) {
    int idx = blockIdx.x * blockDim.x + threadIdx.x;  // e*32 + quad
    int e = idx >> 5;
    if (e >= E) return;
    int q = idx & 31;
    int s = src[e], d = dst[e];
    float4 v = ld4(&x[(size_t)s * H + q * 4]);
    float* p = &agg[(size_t)d * H + q * 4];
    unsafeAtomicAdd(p + 0, v.x);
    unsafeAtomicAdd(p + 1, v.y);
    unsafeAtomicAdd(p + 2, v.z);
    unsafeAtomicAdd(p + 3, v.w);
}

// ---------------- segmented pool over sorted batch: [N,128] -> [G,128] ----------------
__global__ void k_pool(const float* __restrict__ x, const int* __restrict__ batch,
                       float* __restrict__ pool, int nN) {
    int k = threadIdx.x;  // 128
    int c0 = blockIdx.x * POOL_CHUNK;
    if (c0 >= nN) return;
    int c1 = min(c0 + POOL_CHUNK, nN);
    int cur = batch[c0];
    float acc = 0.f;
    for (int i = c0; i < c1; ++i) {
        int bi = batch[i];
        if (bi != cur) {
            unsafeAtomicAdd(&pool[cur * H + k], acc);
            acc = 0.f; cur = bi;
        }
        acc += x[(size_t)i * H + k];
    }
    unsafeAtomicAdd(&pool[cur * H + k], acc);
}

// ---------------- graph-level fc: out = BN(relu((a[+b2][+c3]) @ W + bias)) ----------------
__global__ void k_fc_graph(const float* __restrict__ a, const float* __restrict__ b2,
                           const float* __restrict__ c3,
                           const float* __restrict__ W, const float* __restrict__ bias,
                           const float* __restrict__ g, const float* __restrict__ be,
                           const float* __restrict__ rm, const float* __restrict__ rv,
                           float* __restrict__ out, int K) {
    __shared__ float row[H];
    int gi = blockIdx.x, k = threadIdx.x;
    if (k < K) {
        float v = a[gi * K + k];
        if (b2) v += b2[gi * K + k];
        if (c3) v += c3[gi * K + k];
        row[k] = v;
    }
    __syncthreads();
    float acc = bias[k];
    for (int j = 0; j < K; ++j) acc += row[j] * W[j * H + k];
    acc = fmaxf(acc, 0.f);
    float s = g[k] * rsqrtf(rv[k] + 1e-5f);
    out[gi * H + k] = (acc - rm[k]) * s + be[k];
}

// ---------------- classifier head ----------------
__global__ void k_cls(const float* __restrict__ x2g,
                      const float* __restrict__ Wc1, const float* __restrict__ bc1,
                      const float* __restrict__ gc, const float* __restrict__ bec,
                      const float* __restrict__ rmc, const float* __restrict__ rvc,
                      const float* __restrict__ a_prelu,
                      const float* __restrict__ Wc2, const float* __restrict__ bc2,
                      float* __restrict__ out) {
    __shared__ float row[H];
    __shared__ float hbuf[HC];
    int gi = blockIdx.x, t = threadIdx.x;
    row[t] = x2g[gi * H + t];
    __syncthreads();
    if (t < HC) {
        float acc = bc1[t];
        for (int j = 0; j < H; ++j) acc += row[j] * Wc1[j * HC + t];
        float s = gc[t] * rsqrtf(rvc[t] + 1e-5f);
        acc = (acc - rmc[t]) * s + bec[t];
        float a = a_prelu[0];
        hbuf[t] = acc > 0.f ? acc : a * acc;
    }
    __syncthreads();
    if (t < NOUT) {
        float acc = bc2[t];
        for (int j = 0; j < HC; ++j) acc += hbuf[j] * Wc2[j * NOUT + t];
        out[gi * NOUT + t] = acc;
    }
}

extern "C" void kernel_launch(void* const* d_in, const int* in_sizes, int n_in,
                              void* d_out, int out_size, void* d_ws, size_t ws_size,
                              hipStream_t stream) {
    const int N = kN, E = kE, G = kG;
    const float* pos = (const float*)d_in[0];
    const int* ei    = (const int*)d_in[1];
    const int* batch = (const int*)d_in[2];
    const float* W1a = (const float*)d_in[3];
    const float* b1a = (const float*)d_in[4];
    const float* W1b = (const float*)d_in[5];
    const float* b1b = (const float*)d_in[6];
    const float* n1g = (const float*)d_in[7];
    const float* n1b = (const float*)d_in[8];
    const float* n1rm = (const float*)d_in[9];
    const float* n1rv = (const float*)d_in[10];
    const float* W2a = (const float*)d_in[11];
    const float* b2a = (const float*)d_in[12];
    const float* W2b = (const float*)d_in[13];
    const float* b2b = (const float*)d_in[14];
    const float* n2g = (const float*)d_in[15];
    const float* n2b = (const float*)d_in[16];
    const float* n2rm = (const float*)d_in[17];
    const float* n2rv = (const float*)d_in[18];
    const float* Wf1 = (const float*)d_in[19];
    const float* bf1 = (const float*)d_in[20];
    const float* f1g = (const float*)d_in[21];
    const float* f1b = (const float*)d_in[22];
    const float* f1rm = (const float*)d_in[23];
    const float* f1rv = (const float*)d_in[24];
    const float* Wf2 = (const float*)d_in[25];
    const float* bf2 = (const float*)d_in[26];
    const float* f2g = (const float*)d_in[27];
    const float* f2b = (const float*)d_in[28];
    const float* f2rm = (const float*)d_in[29];
    const float* f2rv = (const float*)d_in[30];
    const float* Wc1 = (const float*)d_in[31];
    const float* bc1 = (const float*)d_in[32];
    const float* gc  = (const float*)d_in[33];
    const float* bec = (const float*)d_in[34];
    const float* rmc = (const float*)d_in[35];
    const float* rvc = (const float*)d_in[36];
    const float* ap  = (const float*)d_in[37];
    const float* Wc2 = (const float*)d_in[38];
    const float* bc2 = (const float*)d_in[39];
    float* out = (float*)d_out;

    float* ws = (float*)d_ws;
    float* xbuf  = ws;                                // N*128
    float* buf2  = xbuf + (size_t)N * H;              // N*128
    float* agg1  = buf2 + (size_t)N * H;              // N*2
    float* ppool = agg1 + (size_t)N * 2;              // G*2
    float* pool1 = ppool + (size_t)G * 2;             // G*128
    float* pool2 = pool1 + (size_t)G * H;             // G*128
    float* x0g   = pool2 + (size_t)G * H;             // G*128
    float* x1g   = x0g + (size_t)G * H;               // G*128
    float* x2g   = x1g + (size_t)G * H;               // G*128

    const int* src  = ei;
    const int* dstp = ei + E;

    // zero: agg1, ppool, pool1, pool2 (contiguous)
    hipMemsetAsync(agg1, 0, (size_t)(N * 2 + G * 2 + 2 * G * H) * sizeof(float), stream);

    // graph-level pos pooling + x0_g
    k_edge_agg_pos<<<(E + 255) / 256, 256, 0, stream>>>(src, dstp, pos, agg1, E);
    k_pool_pos<<<(N + 255) / 256, 256, 0, stream>>>(pos, batch, ppool, N);
    k_fc_graph<<<G, H, 0, stream>>>(ppool, nullptr, nullptr, Wf1, bf1, f1g, f1b, f1rm, f1rv, x0g, 2);

    // GIN1: hA1 = relu((pos+agg1)@W1a+b1a) -> buf2 ; x1 = BN(relu(hA1@W1b+b1b)) -> xbuf
    k_in2<<<(N * 32 + 255) / 256, 256, 0, stream>>>(pos, agg1, W1a, b1a, buf2, N);
    const int mmBlocks = (N + 127) / 128;
    k_mm<false, true><<<mmBlocks, 256, 0, stream>>>(buf2, nullptr, W1b, b1b, n1g, n1b, n1rm, n1rv, xbuf, N);
    k_pool<<<(N + POOL_CHUNK - 1) / POOL_CHUNK, H, 0, stream>>>(xbuf, batch, pool1, N);

    // agg2 = segment_sum(x1[src], dst) -> buf2 (zero first)
    hipMemsetAsync(buf2, 0, (size_t)N * H * sizeof(float), stream);
    k_edge_agg_h<<<(E * 32 + 255) / 256, 256, 0, stream>>>(src, dstp, xbuf, buf2, E);

    // x1_g = fc(x0_g + pool1)
    k_fc_graph<<<G, H, 0, stream>>>(x0g, pool1, nullptr, Wf2, bf2, f2g, f2b, f2rm, f2rv, x1g, H);

    // GIN2: hA2 = relu((x1+agg2)@W2a+b2a) -> buf2 (in place); x2 = BN(relu(hA2@W2b+b2b)) -> xbuf
    k_mm<true, false><<<mmBlocks, 256, 0, stream>>>(xbuf, buf2, W2a, b2a, nullptr, nullptr, nullptr, nullptr, buf2, N);
    k_mm<false, true><<<mmBlocks, 256, 0, stream>>>(buf2, nullptr, W2b, b2b, n2g, n2b, n2rm, n2rv, xbuf, N);
    k_pool<<<(N + POOL_CHUNK - 1) / POOL_CHUNK, H, 0, stream>>>(xbuf, batch, pool2, N);

    // x2_g = fc(x0_g + x1_g + pool2)
    k_fc_graph<<<G, H, 0, stream>>>(x0g, x1g, pool2, Wf2, bf2, f2g, f2b, f2rm, f2rv, x2g, H);

    // classifier
    k_cls<<<G, H, 0, stream>>>(x2g, Wc1, bc1, gc, bec, rmc, rvc, ap, Wc2, bc2, out);
}

// Round 2
// 786.281 us; speedup vs baseline: 2.2479x; 2.2479x over previous
//
#include <hip/hip_runtime.h>

#define H 128
#define HC 64
#define NOUT 10

static constexpr int kN = 100000;
static constexpr int kE = 600000;
static constexpr int kG = 1000;

__device__ __forceinline__ float4 ld4(const float* p) { return *(const float4*)p; }
__device__ __forceinline__ void st4(float* p, float4 v) { *(float4*)p = v; }

// ---------------- histogram: cnt[keys[i]]++ ----------------
__global__ void k_hist(const int* __restrict__ keys, int* __restrict__ cnt, int n) {
    int i = blockIdx.x * blockDim.x + threadIdx.x;
    if (i < n) atomicAdd(&cnt[keys[i]], 1);
}

// ---------------- one-block exclusive scan; optional cursor copy (may alias in) ----------------
__global__ void k_scan(const int* __restrict__ in, int* __restrict__ out,
                       int* __restrict__ cursor, int n) {
    __shared__ int ssum[1024];
    const int t = threadIdx.x;
    const int chunk = (n + 1023) / 1024;
    const int i0 = min(t * chunk, n), i1 = min(i0 + chunk, n);
    int s = 0;
    for (int i = i0; i < i1; ++i) s += in[i];
    ssum[t] = s;
    __syncthreads();
    for (int off = 1; off < 1024; off <<= 1) {
        int v = (t >= off) ? ssum[t - off] : 0;
        __syncthreads();
        ssum[t] += v;
        __syncthreads();
    }
    int base = (t == 0) ? 0 : ssum[t - 1];
    for (int i = i0; i < i1; ++i) {
        int v = in[i];           // read before possible aliased write
        out[i] = base;
        if (cursor) cursor[i] = base;
        base += v;
    }
    if (t == 1023) out[n] = ssum[1023];
}

// ---------------- scatter edges into dst-buckets ----------------
__global__ void k_scatter(const int* __restrict__ src, const int* __restrict__ dst,
                          int* __restrict__ cursor, int* __restrict__ eidx, int E) {
    int e = blockIdx.x * blockDim.x + threadIdx.x;
    if (e >= E) return;
    int slot = atomicAdd(&cursor[dst[e]], 1);
    eidx[slot] = src[e];
}

// ---------------- gather-aggregate pos (C=2) ----------------
__global__ void k_gather_pos(const int* __restrict__ rowptr, const int* __restrict__ eidx,
                             const float* __restrict__ pos, float* __restrict__ agg, int nN) {
    int i = blockIdx.x * blockDim.x + threadIdx.x;
    if (i >= nN) return;
    int j0 = rowptr[i], j1 = rowptr[i + 1];
    float ax = 0.f, ay = 0.f;
    for (int j = j0; j < j1; ++j) {
        float2 p = ((const float2*)pos)[eidx[j]];
        ax += p.x; ay += p.y;
    }
    agg[i * 2 + 0] = ax;
    agg[i * 2 + 1] = ay;
}

// ---------------- gather-aggregate H=128 features; 32 lanes per node ----------------
__global__ void k_gather_h(const int* __restrict__ rowptr, const int* __restrict__ eidx,
                           const float* __restrict__ x, float* __restrict__ agg, int nN) {
    int idx = blockIdx.x * blockDim.x + threadIdx.x;
    int i = idx >> 5, q = idx & 31;
    if (i >= nN) return;
    int j0 = rowptr[i], j1 = rowptr[i + 1];
    float4 acc = make_float4(0.f, 0.f, 0.f, 0.f);
    for (int j = j0; j < j1; ++j) {
        int s = eidx[j];
        float4 v = ld4(&x[(size_t)s * H + q * 4]);
        acc.x += v.x; acc.y += v.y; acc.z += v.z; acc.w += v.w;
    }
    st4(&agg[(size_t)i * H + q * 4], acc);
}

// ---------------- segmented pool, one block per graph (no atomics) ----------------
__global__ void k_pool_seg(const float* __restrict__ x, const int* __restrict__ browptr,
                           float* __restrict__ pool) {
    int g = blockIdx.x, t = threadIdx.x;  // 128 threads
    int r0 = browptr[g], r1 = browptr[g + 1];
    float acc = 0.f;
    for (int r = r0; r < r1; ++r) acc += x[(size_t)r * H + t];
    pool[g * H + t] = acc;
}

__global__ void k_pool_pos_seg(const float* __restrict__ pos, const int* __restrict__ browptr,
                               float* __restrict__ pp) {
    int g = blockIdx.x, t = threadIdx.x;  // 64 threads
    int r0 = browptr[g], r1 = browptr[g + 1];
    float ax = 0.f, ay = 0.f;
    for (int r = r0 + t; r < r1; r += 64) {
        float2 p = ((const float2*)pos)[r];
        ax += p.x; ay += p.y;
    }
    for (int off = 32; off; off >>= 1) {
        ax += __shfl_down(ax, off);
        ay += __shfl_down(ay, off);
    }
    if (t == 0) { pp[g * 2] = ax; pp[g * 2 + 1] = ay; }
}

// ---------------- first GIN1 linear: [N,2] -> [N,128], relu ----------------
__global__ void k_in2(const float* __restrict__ pos, const float* __restrict__ agg,
                      const float* __restrict__ W, const float* __restrict__ b,
                      float* __restrict__ out, int nN) {
    int idx = blockIdx.x * blockDim.x + threadIdx.x;
    int i = idx >> 5, q = idx & 31;
    if (i >= nN) return;
    float2 p = ((const float2*)pos)[i];
    float2 a = ((const float2*)agg)[i];
    float x0 = p.x + a.x, x1 = p.y + a.y;
    float4 w0 = ld4(&W[q * 4]);
    float4 w1 = ld4(&W[H + q * 4]);
    float4 bb = ld4(&b[q * 4]);
    float4 r;
    r.x = fmaxf(x0 * w0.x + x1 * w1.x + bb.x, 0.f);
    r.y = fmaxf(x0 * w0.y + x1 * w1.y + bb.y, 0.f);
    r.z = fmaxf(x0 * w0.z + x1 * w1.z + bb.z, 0.f);
    r.w = fmaxf(x0 * w0.w + x1 * w1.w + bb.w, 0.f);
    st4(&out[(size_t)i * H + q * 4], r);
}

// ---------------- main matmul: OUT = [BN](relu((IN1[+IN2]) @ W + b)) ----------------
template <bool HAS_IN2, bool HAS_BN>
__global__ __launch_bounds__(256) void k_mm(
    const float* __restrict__ in1, const float* __restrict__ in2,
    const float* __restrict__ W, const float* __restrict__ bias,
    const float* __restrict__ bn_g, const float* __restrict__ bn_b,
    const float* __restrict__ bn_rm, const float* __restrict__ bn_rv,
    float* __restrict__ out, int nN) {
    __shared__ float Ws[H * H];
    __shared__ float As[32 * H];
    const int t = threadIdx.x;

#pragma unroll
    for (int r = 0; r < 16; ++r) {
        int idx = r * 1024 + t * 4;
        st4(&Ws[idx], ld4(&W[idx]));
    }

    const int kq = t & 31;
    const int f0 = kq * 4;
    const int ng4 = (t >> 5) * 4;
    const float4 b4 = ld4(&bias[f0]);

    float4 s4, sh4;
    if (HAS_BN) {
        float4 g = ld4(&bn_g[f0]);
        float4 be = ld4(&bn_b[f0]);
        float4 rm = ld4(&bn_rm[f0]);
        float4 rv = ld4(&bn_rv[f0]);
        s4.x = g.x * rsqrtf(rv.x + 1e-5f); s4.y = g.y * rsqrtf(rv.y + 1e-5f);
        s4.z = g.z * rsqrtf(rv.z + 1e-5f); s4.w = g.w * rsqrtf(rv.w + 1e-5f);
        sh4.x = be.x - rm.x * s4.x; sh4.y = be.y - rm.y * s4.y;
        sh4.z = be.z - rm.z * s4.z; sh4.w = be.w - rm.w * s4.w;
    }

    const int base = blockIdx.x * 128;
    for (int it = 0; it < 4; ++it) {
        const int n0 = base + it * 32;
        __syncthreads();
#pragma unroll
        for (int r = 0; r < 4; ++r) {
            int idx = r * 1024 + t * 4;
            int row = idx >> 7, col = idx & 127;
            int node = n0 + row;
            float4 v = make_float4(0.f, 0.f, 0.f, 0.f);
            if (node < nN) {
                v = ld4(&in1[(size_t)node * H + col]);
                if (HAS_IN2) {
                    float4 u = ld4(&in2[(size_t)node * H + col]);
                    v.x += u.x; v.y += u.y; v.z += u.z; v.w += u.w;
                }
            }
            st4(&As[row * H + col], v);
        }
        __syncthreads();

        float4 acc[4] = {b4, b4, b4, b4};
#pragma unroll 8
        for (int j = 0; j < H; j += 4) {
            const float4 w0 = ld4(&Ws[(j + 0) * H + f0]);
            const float4 w1 = ld4(&Ws[(j + 1) * H + f0]);
            const float4 w2 = ld4(&Ws[(j + 2) * H + f0]);
            const float4 w3 = ld4(&Ws[(j + 3) * H + f0]);
#pragma unroll
            for (int n = 0; n < 4; ++n) {
                const float4 a = ld4(&As[(ng4 + n) * H + j]);
                acc[n].x += a.x * w0.x + a.y * w1.x + a.z * w2.x + a.w * w3.x;
                acc[n].y += a.x * w0.y + a.y * w1.y + a.z * w2.y + a.w * w3.y;
                acc[n].z += a.x * w0.z + a.y * w1.z + a.z * w2.z + a.w * w3.z;
                acc[n].w += a.x * w0.w + a.y * w1.w + a.z * w2.w + a.w * w3.w;
            }
        }

#pragma unroll
        for (int n = 0; n < 4; ++n) {
            const int node = n0 + ng4 + n;
            if (node < nN) {
                float4 v = acc[n];
                v.x = fmaxf(v.x, 0.f); v.y = fmaxf(v.y, 0.f);
                v.z = fmaxf(v.z, 0.f); v.w = fmaxf(v.w, 0.f);
                if (HAS_BN) {
                    v.x = v.x * s4.x + sh4.x; v.y = v.y * s4.y + sh4.y;
                    v.z = v.z * s4.z + sh4.z; v.w = v.w * s4.w + sh4.w;
                }
                st4(&out[(size_t)node * H + f0], v);
            }
        }
    }
}

// ---------------- graph-level fc ----------------
__global__ void k_fc_graph(const float* __restrict__ a, const float* __restrict__ b2,
                           const float* __restrict__ c3,
                           const float* __restrict__ W, const float* __restrict__ bias,
                           const float* __restrict__ g, const float* __restrict__ be,
                           const float* __restrict__ rm, const float* __restrict__ rv,
                           float* __restrict__ out, int K) {
    __shared__ float row[H];
    int gi = blockIdx.x, k = threadIdx.x;
    if (k < K) {
        float v = a[gi * K + k];
        if (b2) v += b2[gi * K + k];
        if (c3) v += c3[gi * K + k];
        row[k] = v;
    }
    __syncthreads();
    float acc = bias[k];
    for (int j = 0; j < K; ++j) acc += row[j] * W[j * H + k];
    acc = fmaxf(acc, 0.f);
    float s = g[k] * rsqrtf(rv[k] + 1e-5f);
    out[gi * H + k] = (acc - rm[k]) * s + be[k];
}

// ---------------- classifier head ----------------
__global__ void k_cls(const float* __restrict__ x2g,
                      const float* __restrict__ Wc1, const float* __restrict__ bc1,
                      const float* __restrict__ gc, const float* __restrict__ bec,
                      const float* __restrict__ rmc, const float* __restrict__ rvc,
                      const float* __restrict__ a_prelu,
                      const float* __restrict__ Wc2, const float* __restrict__ bc2,
                      float* __restrict__ out) {
    __shared__ float row[H];
    __shared__ float hbuf[HC];
    int gi = blockIdx.x, t = threadIdx.x;
    row[t] = x2g[gi * H + t];
    __syncthreads();
    if (t < HC) {
        float acc = bc1[t];
        for (int j = 0; j < H; ++j) acc += row[j] * Wc1[j * HC + t];
        float s = gc[t] * rsqrtf(rvc[t] + 1e-5f);
        acc = (acc - rmc[t]) * s + bec[t];
        float a = a_prelu[0];
        hbuf[t] = acc > 0.f ? acc : a * acc;
    }
    __syncthreads();
    if (t < NOUT) {
        float acc = bc2[t];
        for (int j = 0; j < HC; ++j) acc += hbuf[j] * Wc2[j * NOUT + t];
        out[gi * NOUT + t] = acc;
    }
}

extern "C" void kernel_launch(void* const* d_in, const int* in_sizes, int n_in,
                              void* d_out, int out_size, void* d_ws, size_t ws_size,
                              hipStream_t stream) {
    const int N = kN, E = kE, G = kG;
    const float* pos = (const float*)d_in[0];
    const int* ei    = (const int*)d_in[1];
    const int* batch = (const int*)d_in[2];
    const float* W1a = (const float*)d_in[3];
    const float* b1a = (const float*)d_in[4];
    const float* W1b = (const float*)d_in[5];
    const float* b1b = (const float*)d_in[6];
    const float* n1g = (const float*)d_in[7];
    const float* n1b = (const float*)d_in[8];
    const float* n1rm = (const float*)d_in[9];
    const float* n1rv = (const float*)d_in[10];
    const float* W2a = (const float*)d_in[11];
    const float* b2a = (const float*)d_in[12];
    const float* W2b = (const float*)d_in[13];
    const float* b2b = (const float*)d_in[14];
    const float* n2g = (const float*)d_in[15];
    const float* n2b = (const float*)d_in[16];
    const float* n2rm = (const float*)d_in[17];
    const float* n2rv = (const float*)d_in[18];
    const float* Wf1 = (const float*)d_in[19];
    const float* bf1 = (const float*)d_in[20];
    const float* f1g = (const float*)d_in[21];
    const float* f1b = (const float*)d_in[22];
    const float* f1rm = (const float*)d_in[23];
    const float* f1rv = (const float*)d_in[24];
    const float* Wf2 = (const float*)d_in[25];
    const float* bf2 = (const float*)d_in[26];
    const float* f2g = (const float*)d_in[27];
    const float* f2b = (const float*)d_in[28];
    const float* f2rm = (const float*)d_in[29];
    const float* f2rv = (const float*)d_in[30];
    const float* Wc1 = (const float*)d_in[31];
    const float* bc1 = (const float*)d_in[32];
    const float* gc  = (const float*)d_in[33];
    const float* bec = (const float*)d_in[34];
    const float* rmc = (const float*)d_in[35];
    const float* rvc = (const float*)d_in[36];
    const float* ap  = (const float*)d_in[37];
    const float* Wc2 = (const float*)d_in[38];
    const float* bc2 = (const float*)d_in[39];
    float* out = (float*)d_out;

    // ---- workspace layout ----
    float* ws = (float*)d_ws;
    float* xbuf  = ws;                                // N*H
    float* buf2  = xbuf + (size_t)N * H;              // N*H
    float* aggp  = buf2 + (size_t)N * H;              // N*2
    float* ppool = aggp + (size_t)N * 2;              // G*2
    float* pool1 = ppool + (size_t)G * 2;             // G*H
    float* pool2 = pool1 + (size_t)G * H;             // G*H
    float* x0g   = pool2 + (size_t)G * H;             // G*H
    float* x1g   = x0g + (size_t)G * H;               // G*H
    float* x2g   = x1g + (size_t)G * H;               // G*H
    int* ints    = (int*)(x2g + (size_t)G * H);
    int* deg     = ints;                              // N (reused as cursor)
    int* bcnt    = deg + N;                           // G (scratch)
    int* rowptr  = bcnt + G;                          // N+1
    int* browptr = rowptr + N + 1;                    // G+1
    int* eidx    = browptr + G + 1;                   // E

    const int* src  = ei;
    const int* dstp = ei + E;

    // ---- CSR build (by dst) + batch boundaries ----
    hipMemsetAsync(deg, 0, (size_t)(N + G) * sizeof(int), stream);  // deg + bcnt
    k_hist<<<(E + 255) / 256, 256, 0, stream>>>(dstp, deg, E);
    k_hist<<<(N + 255) / 256, 256, 0, stream>>>(batch, bcnt, N);
    k_scan<<<1, 1024, 0, stream>>>(deg, rowptr, deg /*cursor aliases deg*/, N);
    k_scan<<<1, 1024, 0, stream>>>(bcnt, browptr, nullptr, G);
    k_scatter<<<(E + 255) / 256, 256, 0, stream>>>(src, dstp, deg, eidx, E);

    // ---- graph-level pos pooling + x0_g ----
    k_gather_pos<<<(N + 255) / 256, 256, 0, stream>>>(rowptr, eidx, pos, aggp, N);
    k_pool_pos_seg<<<G, 64, 0, stream>>>(pos, browptr, ppool);
    k_fc_graph<<<G, H, 0, stream>>>(ppool, nullptr, nullptr, Wf1, bf1, f1g, f1b, f1rm, f1rv, x0g, 2);

    // ---- GIN1 ----
    k_in2<<<(N * 32 + 255) / 256, 256, 0, stream>>>(pos, aggp, W1a, b1a, buf2, N);
    const int mmBlocks = (N + 127) / 128;
    k_mm<false, true><<<mmBlocks, 256, 0, stream>>>(buf2, nullptr, W1b, b1b, n1g, n1b, n1rm, n1rv, xbuf, N);

    // agg2 = gather(x1) -> buf2 (buf2 free after k_mm above)
    k_gather_h<<<(N * 32 + 255) / 256, 256, 0, stream>>>(rowptr, eidx, xbuf, buf2, N);
    k_pool_seg<<<G, H, 0, stream>>>(xbuf, browptr, pool1);
    k_fc_graph<<<G, H, 0, stream>>>(x0g, pool1, nullptr, Wf2, bf2, f2g, f2b, f2rm, f2rv, x1g, H);

    // ---- GIN2 ----
    k_mm<true, false><<<mmBlocks, 256, 0, stream>>>(xbuf, buf2, W2a, b2a, nullptr, nullptr, nullptr, nullptr, buf2, N);
    k_mm<false, true><<<mmBlocks, 256, 0, stream>>>(buf2, nullptr, W2b, b2b, n2g, n2b, n2rm, n2rv, xbuf, N);
    k_pool_seg<<<G, H, 0, stream>>>(xbuf, browptr, pool2);
    k_fc_graph<<<G, H, 0, stream>>>(x0g, x1g, pool2, Wf2, bf2, f2g, f2b, f2rm, f2rv, x2g, H);

    // ---- classifier ----
    k_cls<<<G, H, 0, stream>>>(x2g, Wc1, bc1, gc, bec, rmc, rvc, ap, Wc2, bc2, out);
}

// Round 3
// 538.377 us; speedup vs baseline: 3.2830x; 1.4605x over previous
//
#include <hip/hip_runtime.h>

#define H 128
#define HC 64
#define NOUT 10

static constexpr int kN = 100000;
static constexpr int kE = 600000;
static constexpr int kG = 1000;

__device__ __forceinline__ float4 ld4(const float* p) { return *(const float4*)p; }
__device__ __forceinline__ void st4(float* p, float4 v) { *(float4*)p = v; }

// ---------------- histogram: cnt[keys[i]]++ ----------------
__global__ void k_hist(const int* __restrict__ keys, int* __restrict__ cnt, int n) {
    int i = blockIdx.x * blockDim.x + threadIdx.x;
    if (i < n) atomicAdd(&cnt[keys[i]], 1);
}

// ---------------- hierarchical scan: pass1 block sums (1024 elems/block) ----------------
__global__ void k_scan_p1(const int* __restrict__ in, int* __restrict__ partial, int n) {
    __shared__ int red[256];
    int b = blockIdx.x, t = threadIdx.x;
    int base = b * 1024 + t * 4;
    int s = 0;
#pragma unroll
    for (int k = 0; k < 4; ++k) {
        int j = base + k;
        if (j < n) s += in[j];
    }
    red[t] = s;
    __syncthreads();
    for (int off = 128; off; off >>= 1) {
        if (t < off) red[t] += red[t + off];
        __syncthreads();
    }
    if (t == 0) partial[b] = red[0];
}

// ---------------- pass2: single-block exclusive scan of partials (nb <= 1024) ----------------
__global__ void k_scan_p2(int* __restrict__ partial, int* __restrict__ total_out, int nb) {
    __shared__ int ssum[1024];
    int t = threadIdx.x;
    int v = (t < nb) ? partial[t] : 0;
    ssum[t] = v;
    __syncthreads();
    for (int off = 1; off < 1024; off <<= 1) {
        int u = (t >= off) ? ssum[t - off] : 0;
        __syncthreads();
        ssum[t] += u;
        __syncthreads();
    }
    if (t < nb) partial[t] = ssum[t] - v;  // exclusive
    if (t == 1023 && total_out) *total_out = ssum[1023];
}

// ---------------- pass3: per-block exclusive scan + base; writes out and cursor ----------------
// cursor may alias in (read-before-write within owning thread).
__global__ void k_scan_p3(const int* __restrict__ in, const int* __restrict__ partial,
                          int* __restrict__ out, int* __restrict__ cursor, int n) {
    __shared__ int red[256];
    int b = blockIdx.x, t = threadIdx.x;
    int base = b * 1024 + t * 4;
    int v[4];
    int s = 0;
#pragma unroll
    for (int k = 0; k < 4; ++k) {
        int j = base + k;
        v[k] = (j < n) ? in[j] : 0;
        s += v[k];
    }
    red[t] = s;
    __syncthreads();
    // inclusive butterfly scan over thread sums
    for (int off = 1; off < 256; off <<= 1) {
        int u = (t >= off) ? red[t - off] : 0;
        __syncthreads();
        red[t] += u;
        __syncthreads();
    }
    int tbase = partial[b] + red[t] - s;  // exclusive base for this thread
#pragma unroll
    for (int k = 0; k < 4; ++k) {
        int j = base + k;
        if (j < n) {
            out[j] = tbase;
            if (cursor) cursor[j] = tbase;
            tbase += v[k];
        }
    }
}

// ---------------- browptr via binary search on sorted batch ----------------
__global__ void k_bsearch(const int* __restrict__ batch, int* __restrict__ browptr,
                          int nN, int nG) {
    int g = blockIdx.x * blockDim.x + threadIdx.x;
    if (g > nG) return;
    int lo = 0, hi = nN;
    while (lo < hi) {
        int mid = (lo + hi) >> 1;
        if (batch[mid] < g) lo = mid + 1; else hi = mid;
    }
    browptr[g] = lo;
}

// ---------------- scatter edges into dst-buckets ----------------
__global__ void k_scatter(const int* __restrict__ src, const int* __restrict__ dst,
                          int* __restrict__ cursor, int* __restrict__ eidx, int E) {
    int e = blockIdx.x * blockDim.x + threadIdx.x;
    if (e >= E) return;
    int slot = atomicAdd(&cursor[dst[e]], 1);
    eidx[slot] = src[e];
}

// ---------------- gather-aggregate pos (C=2) ----------------
__global__ void k_gather_pos(const int* __restrict__ rowptr, const int* __restrict__ eidx,
                             const float* __restrict__ pos, float* __restrict__ agg, int nN) {
    int i = blockIdx.x * blockDim.x + threadIdx.x;
    if (i >= nN) return;
    int j0 = rowptr[i], j1 = rowptr[i + 1];
    float ax = 0.f, ay = 0.f;
    for (int j = j0; j < j1; ++j) {
        float2 p = ((const float2*)pos)[eidx[j]];
        ax += p.x; ay += p.y;
    }
    agg[i * 2 + 0] = ax;
    agg[i * 2 + 1] = ay;
}

// ---------------- gather-aggregate H=128 features; 32 lanes per node ----------------
__global__ void k_gather_h(const int* __restrict__ rowptr, const int* __restrict__ eidx,
                           const float* __restrict__ x, float* __restrict__ agg, int nN) {
    int idx = blockIdx.x * blockDim.x + threadIdx.x;
    int i = idx >> 5, q = idx & 31;
    if (i >= nN) return;
    int j0 = rowptr[i], j1 = rowptr[i + 1];
    float4 acc = make_float4(0.f, 0.f, 0.f, 0.f);
    for (int j = j0; j < j1; ++j) {
        int s = eidx[j];
        float4 v = ld4(&x[(size_t)s * H + q * 4]);
        acc.x += v.x; acc.y += v.y; acc.z += v.z; acc.w += v.w;
    }
    st4(&agg[(size_t)i * H + q * 4], acc);
}

// ---------------- segmented pool, one block per graph (no atomics) ----------------
__global__ void k_pool_seg(const float* __restrict__ x, const int* __restrict__ browptr,
                           float* __restrict__ pool) {
    int g = blockIdx.x, t = threadIdx.x;  // 128 threads
    int r0 = browptr[g], r1 = browptr[g + 1];
    float acc = 0.f;
    for (int r = r0; r < r1; ++r) acc += x[(size_t)r * H + t];
    pool[g * H + t] = acc;
}

__global__ void k_pool_pos_seg(const float* __restrict__ pos, const int* __restrict__ browptr,
                               float* __restrict__ pp) {
    int g = blockIdx.x, t = threadIdx.x;  // 64 threads
    int r0 = browptr[g], r1 = browptr[g + 1];
    float ax = 0.f, ay = 0.f;
    for (int r = r0 + t; r < r1; r += 64) {
        float2 p = ((const float2*)pos)[r];
        ax += p.x; ay += p.y;
    }
    for (int off = 32; off; off >>= 1) {
        ax += __shfl_down(ax, off);
        ay += __shfl_down(ay, off);
    }
    if (t == 0) { pp[g * 2] = ax; pp[g * 2 + 1] = ay; }
}

// ---------------- first GIN1 linear: [N,2] -> [N,128], relu ----------------
__global__ void k_in2(const float* __restrict__ pos, const float* __restrict__ agg,
                      const float* __restrict__ W, const float* __restrict__ b,
                      float* __restrict__ out, int nN) {
    int idx = blockIdx.x * blockDim.x + threadIdx.x;
    int i = idx >> 5, q = idx & 31;
    if (i >= nN) return;
    float2 p = ((const float2*)pos)[i];
    float2 a = ((const float2*)agg)[i];
    float x0 = p.x + a.x, x1 = p.y + a.y;
    float4 w0 = ld4(&W[q * 4]);
    float4 w1 = ld4(&W[H + q * 4]);
    float4 bb = ld4(&b[q * 4]);
    float4 r;
    r.x = fmaxf(x0 * w0.x + x1 * w1.x + bb.x, 0.f);
    r.y = fmaxf(x0 * w0.y + x1 * w1.y + bb.y, 0.f);
    r.z = fmaxf(x0 * w0.z + x1 * w1.z + bb.z, 0.f);
    r.w = fmaxf(x0 * w0.w + x1 * w1.w + bb.w, 0.f);
    st4(&out[(size_t)i * H + q * 4], r);
}

// ---------------- main matmul: OUT = [BN](relu((IN1[+IN2]) @ W + b)) ----------------
template <bool HAS_IN2, bool HAS_BN>
__global__ __launch_bounds__(256) void k_mm(
    const float* __restrict__ in1, const float* __restrict__ in2,
    const float* __restrict__ W, const float* __restrict__ bias,
    const float* __restrict__ bn_g, const float* __restrict__ bn_b,
    const float* __restrict__ bn_rm, const float* __restrict__ bn_rv,
    float* __restrict__ out, int nN) {
    __shared__ float Ws[H * H];
    __shared__ float As[32 * H];
    const int t = threadIdx.x;

#pragma unroll
    for (int r = 0; r < 16; ++r) {
        int idx = r * 1024 + t * 4;
        st4(&Ws[idx], ld4(&W[idx]));
    }

    const int kq = t & 31;
    const int f0 = kq * 4;
    const int ng4 = (t >> 5) * 4;
    const float4 b4 = ld4(&bias[f0]);

    float4 s4, sh4;
    if (HAS_BN) {
        float4 g = ld4(&bn_g[f0]);
        float4 be = ld4(&bn_b[f0]);
        float4 rm = ld4(&bn_rm[f0]);
        float4 rv = ld4(&bn_rv[f0]);
        s4.x = g.x * rsqrtf(rv.x + 1e-5f); s4.y = g.y * rsqrtf(rv.y + 1e-5f);
        s4.z = g.z * rsqrtf(rv.z + 1e-5f); s4.w = g.w * rsqrtf(rv.w + 1e-5f);
        sh4.x = be.x - rm.x * s4.x; sh4.y = be.y - rm.y * s4.y;
        sh4.z = be.z - rm.z * s4.z; sh4.w = be.w - rm.w * s4.w;
    }

    const int base = blockIdx.x * 128;
    for (int it = 0; it < 4; ++it) {
        const int n0 = base + it * 32;
        __syncthreads();
#pragma unroll
        for (int r = 0; r < 4; ++r) {
            int idx = r * 1024 + t * 4;
            int row = idx >> 7, col = idx & 127;
            int node = n0 + row;
            float4 v = make_float4(0.f, 0.f, 0.f, 0.f);
            if (node < nN) {
                v = ld4(&in1[(size_t)node * H + col]);
                if (HAS_IN2) {
                    float4 u = ld4(&in2[(size_t)node * H + col]);
                    v.x += u.x; v.y += u.y; v.z += u.z; v.w += u.w;
                }
            }
            st4(&As[row * H + col], v);
        }
        __syncthreads();

        float4 acc[4] = {b4, b4, b4, b4};
#pragma unroll 8
        for (int j = 0; j < H; j += 4) {
            const float4 w0 = ld4(&Ws[(j + 0) * H + f0]);
            const float4 w1 = ld4(&Ws[(j + 1) * H + f0]);
            const float4 w2 = ld4(&Ws[(j + 2) * H + f0]);
            const float4 w3 = ld4(&Ws[(j + 3) * H + f0]);
#pragma unroll
            for (int n = 0; n < 4; ++n) {
                const float4 a = ld4(&As[(ng4 + n) * H + j]);
                acc[n].x += a.x * w0.x + a.y * w1.x + a.z * w2.x + a.w * w3.x;
                acc[n].y += a.x * w0.y + a.y * w1.y + a.z * w2.y + a.w * w3.y;
                acc[n].z += a.x * w0.z + a.y * w1.z + a.z * w2.z + a.w * w3.z;
                acc[n].w += a.x * w0.w + a.y * w1.w + a.z * w2.w + a.w * w3.w;
            }
        }

#pragma unroll
        for (int n = 0; n < 4; ++n) {
            const int node = n0 + ng4 + n;
            if (node < nN) {
                float4 v = acc[n];
                v.x = fmaxf(v.x, 0.f); v.y = fmaxf(v.y, 0.f);
                v.z = fmaxf(v.z, 0.f); v.w = fmaxf(v.w, 0.f);
                if (HAS_BN) {
                    v.x = v.x * s4.x + sh4.x; v.y = v.y * s4.y + sh4.y;
                    v.z = v.z * s4.z + sh4.z; v.w = v.w * s4.w + sh4.w;
                }
                st4(&out[(size_t)node * H + f0], v);
            }
        }
    }
}

// ---------------- graph-level fc ----------------
__global__ void k_fc_graph(const float* __restrict__ a, const float* __restrict__ b2,
                           const float* __restrict__ c3,
                           const float* __restrict__ W, const float* __restrict__ bias,
                           const float* __restrict__ g, const float* __restrict__ be,
                           const float* __restrict__ rm, const float* __restrict__ rv,
                           float* __restrict__ out, int K) {
    __shared__ float row[H];
    int gi = blockIdx.x, k = threadIdx.x;
    if (k < K) {
        float v = a[gi * K + k];
        if (b2) v += b2[gi * K + k];
        if (c3) v += c3[gi * K + k];
        row[k] = v;
    }
    __syncthreads();
    float acc = bias[k];
    for (int j = 0; j < K; ++j) acc += row[j] * W[j * H + k];
    acc = fmaxf(acc, 0.f);
    float s = g[k] * rsqrtf(rv[k] + 1e-5f);
    out[gi * H + k] = (acc - rm[k]) * s + be[k];
}

// ---------------- classifier head ----------------
__global__ void k_cls(const float* __restrict__ x2g,
                      const float* __restrict__ Wc1, const float* __restrict__ bc1,
                      const float* __restrict__ gc, const float* __restrict__ bec,
                      const float* __restrict__ rmc, const float* __restrict__ rvc,
                      const float* __restrict__ a_prelu,
                      const float* __restrict__ Wc2, const float* __restrict__ bc2,
                      float* __restrict__ out) {
    __shared__ float row[H];
    __shared__ float hbuf[HC];
    int gi = blockIdx.x, t = threadIdx.x;
    row[t] = x2g[gi * H + t];
    __syncthreads();
    if (t < HC) {
        float acc = bc1[t];
        for (int j = 0; j < H; ++j) acc += row[j] * Wc1[j * HC + t];
        float s = gc[t] * rsqrtf(rvc[t] + 1e-5f);
        acc = (acc - rmc[t]) * s + bec[t];
        float a = a_prelu[0];
        hbuf[t] = acc > 0.f ? acc : a * acc;
    }
    __syncthreads();
    if (t < NOUT) {
        float acc = bc2[t];
        for (int j = 0; j < HC; ++j) acc += hbuf[j] * Wc2[j * NOUT + t];
        out[gi * NOUT + t] = acc;
    }
}

extern "C" void kernel_launch(void* const* d_in, const int* in_sizes, int n_in,
                              void* d_out, int out_size, void* d_ws, size_t ws_size,
                              hipStream_t stream) {
    const int N = kN, E = kE, G = kG;
    const float* pos = (const float*)d_in[0];
    const int* ei    = (const int*)d_in[1];
    const int* batch = (const int*)d_in[2];
    const float* W1a = (const float*)d_in[3];
    const float* b1a = (const float*)d_in[4];
    const float* W1b = (const float*)d_in[5];
    const float* b1b = (const float*)d_in[6];
    const float* n1g = (const float*)d_in[7];
    const float* n1b = (const float*)d_in[8];
    const float* n1rm = (const float*)d_in[9];
    const float* n1rv = (const float*)d_in[10];
    const float* W2a = (const float*)d_in[11];
    const float* b2a = (const float*)d_in[12];
    const float* W2b = (const float*)d_in[13];
    const float* b2b = (const float*)d_in[14];
    const float* n2g = (const float*)d_in[15];
    const float* n2b = (const float*)d_in[16];
    const float* n2rm = (const float*)d_in[17];
    const float* n2rv = (const float*)d_in[18];
    const float* Wf1 = (const float*)d_in[19];
    const float* bf1 = (const float*)d_in[20];
    const float* f1g = (const float*)d_in[21];
    const float* f1b = (const float*)d_in[22];
    const float* f1rm = (const float*)d_in[23];
    const float* f1rv = (const float*)d_in[24];
    const float* Wf2 = (const float*)d_in[25];
    const float* bf2 = (const float*)d_in[26];
    const float* f2g = (const float*)d_in[27];
    const float* f2b = (const float*)d_in[28];
    const float* f2rm = (const float*)d_in[29];
    const float* f2rv = (const float*)d_in[30];
    const float* Wc1 = (const float*)d_in[31];
    const float* bc1 = (const float*)d_in[32];
    const float* gc  = (const float*)d_in[33];
    const float* bec = (const float*)d_in[34];
    const float* rmc = (const float*)d_in[35];
    const float* rvc = (const float*)d_in[36];
    const float* ap  = (const float*)d_in[37];
    const float* Wc2 = (const float*)d_in[38];
    const float* bc2 = (const float*)d_in[39];
    float* out = (float*)d_out;

    // ---- workspace layout ----
    float* ws = (float*)d_ws;
    float* xbuf  = ws;                                // N*H
    float* buf2  = xbuf + (size_t)N * H;              // N*H
    float* aggp  = buf2 + (size_t)N * H;              // N*2
    float* ppool = aggp + (size_t)N * 2;              // G*2
    float* pool1 = ppool + (size_t)G * 2;             // G*H
    float* pool2 = pool1 + (size_t)G * H;             // G*H
    float* x0g   = pool2 + (size_t)G * H;             // G*H
    float* x1g   = x0g + (size_t)G * H;               // G*H
    float* x2g   = x1g + (size_t)G * H;               // G*H
    int* ints    = (int*)(x2g + (size_t)G * H);
    int* deg     = ints;                              // N (reused as cursor)
    int* rowptr  = deg + N;                           // N+1
    int* browptr = rowptr + N + 1;                    // G+1
    int* partial = browptr + G + 1;                   // ceil(N/1024)
    int* eidx    = partial + 1024;                    // E

    const int* src  = ei;
    const int* dstp = ei + E;

    const int nb = (N + 1023) / 1024;  // 98 blocks

    // ---- CSR build (by dst) + batch boundaries ----
    hipMemsetAsync(deg, 0, (size_t)N * sizeof(int), stream);
    k_hist<<<(E + 255) / 256, 256, 0, stream>>>(dstp, deg, E);
    k_bsearch<<<(G + 256) / 256, 256, 0, stream>>>(batch, browptr, N, G);
    k_scan_p1<<<nb, 256, 0, stream>>>(deg, partial, N);
    k_scan_p2<<<1, 1024, 0, stream>>>(partial, rowptr + N, nb);
    k_scan_p3<<<nb, 256, 0, stream>>>(deg, partial, rowptr, deg /*cursor aliases deg*/, N);
    k_scatter<<<(E + 255) / 256, 256, 0, stream>>>(src, dstp, deg, eidx, E);

    // ---- graph-level pos pooling + x0_g ----
    k_gather_pos<<<(N + 255) / 256, 256, 0, stream>>>(rowptr, eidx, pos, aggp, N);
    k_pool_pos_seg<<<G, 64, 0, stream>>>(pos, browptr, ppool);
    k_fc_graph<<<G, H, 0, stream>>>(ppool, nullptr, nullptr, Wf1, bf1, f1g, f1b, f1rm, f1rv, x0g, 2);

    // ---- GIN1 ----
    k_in2<<<(N * 32 + 255) / 256, 256, 0, stream>>>(pos, aggp, W1a, b1a, buf2, N);
    const int mmBlocks = (N + 127) / 128;
    k_mm<false, true><<<mmBlocks, 256, 0, stream>>>(buf2, nullptr, W1b, b1b, n1g, n1b, n1rm, n1rv, xbuf, N);

    // agg2 = gather(x1) -> buf2
    k_gather_h<<<(N * 32 + 255) / 256, 256, 0, stream>>>(rowptr, eidx, xbuf, buf2, N);
    k_pool_seg<<<G, H, 0, stream>>>(xbuf, browptr, pool1);
    k_fc_graph<<<G, H, 0, stream>>>(x0g, pool1, nullptr, Wf2, bf2, f2g, f2b, f2rm, f2rv, x1g, H);

    // ---- GIN2 ----
    k_mm<true, false><<<mmBlocks, 256, 0, stream>>>(xbuf, buf2, W2a, b2a, nullptr, nullptr, nullptr, nullptr, buf2, N);
    k_mm<false, true><<<mmBlocks, 256, 0, stream>>>(buf2, nullptr, W2b, b2b, n2g, n2b, n2rm, n2rv, xbuf, N);
    k_pool_seg<<<G, H, 0, stream>>>(xbuf, browptr, pool2);
    k_fc_graph<<<G, H, 0, stream>>>(x0g, x1g, pool2, Wf2, bf2, f2g, f2b, f2rm, f2rv, x2g, H);

    // ---- classifier ----
    k_cls<<<G, H, 0, stream>>>(x2g, Wc1, bc1, gc, bec, rmc, rvc, ap, Wc2, bc2, out);
}

// Round 4
// 290.887 us; speedup vs baseline: 6.0762x; 1.8508x over previous
//
#include <hip/hip_runtime.h>

#define H 128
#define HC 64
#define NOUT 10

static constexpr int kN = 100000;
static constexpr int kE = 600000;
static constexpr int kG = 1000;

typedef __attribute__((ext_vector_type(8))) short short8v;
typedef __attribute__((ext_vector_type(4))) float f32x4;

__device__ __forceinline__ float4 ld4(const float* p) { return *(const float4*)p; }
__device__ __forceinline__ void st4(float* p, float4 v) { *(float4*)p = v; }

// fp32 -> bf16 round-to-nearest-even
__device__ __forceinline__ unsigned f2bf(float f) {
    unsigned u = __float_as_uint(f);
    return (u + 0x7fffu + ((u >> 16) & 1u)) >> 16;
}
__device__ __forceinline__ unsigned f2bf2(float a, float b) {
    return f2bf(a) | (f2bf(b) << 16);
}
__device__ __forceinline__ float bf2f(unsigned short u) {
    return __uint_as_float(((unsigned)u) << 16);
}
__device__ __forceinline__ void unpack_add8(uint4 u, float* a) {
    a[0] += __uint_as_float(u.x << 16); a[1] += __uint_as_float(u.x & 0xFFFF0000u);
    a[2] += __uint_as_float(u.y << 16); a[3] += __uint_as_float(u.y & 0xFFFF0000u);
    a[4] += __uint_as_float(u.z << 16); a[5] += __uint_as_float(u.z & 0xFFFF0000u);
    a[6] += __uint_as_float(u.w << 16); a[7] += __uint_as_float(u.w & 0xFFFF0000u);
}

// ---------------- histogram: cnt[keys[i]]++ ----------------
__global__ void k_hist(const int* __restrict__ keys, int* __restrict__ cnt, int n) {
    int i = blockIdx.x * blockDim.x + threadIdx.x;
    if (i < n) atomicAdd(&cnt[keys[i]], 1);
}

// ---------------- hierarchical scan ----------------
__global__ void k_scan_p1(const int* __restrict__ in, int* __restrict__ partial, int n) {
    __shared__ int red[256];
    int b = blockIdx.x, t = threadIdx.x;
    int base = b * 1024 + t * 4;
    int s = 0;
#pragma unroll
    for (int k = 0; k < 4; ++k) {
        int j = base + k;
        if (j < n) s += in[j];
    }
    red[t] = s;
    __syncthreads();
    for (int off = 128; off; off >>= 1) {
        if (t < off) red[t] += red[t + off];
        __syncthreads();
    }
    if (t == 0) partial[b] = red[0];
}

__global__ void k_scan_p2(int* __restrict__ partial, int* __restrict__ total_out, int nb) {
    __shared__ int ssum[1024];
    int t = threadIdx.x;
    int v = (t < nb) ? partial[t] : 0;
    ssum[t] = v;
    __syncthreads();
    for (int off = 1; off < 1024; off <<= 1) {
        int u = (t >= off) ? ssum[t - off] : 0;
        __syncthreads();
        ssum[t] += u;
        __syncthreads();
    }
    if (t < nb) partial[t] = ssum[t] - v;
    if (t == 1023 && total_out) *total_out = ssum[1023];
}

__global__ void k_scan_p3(const int* __restrict__ in, const int* __restrict__ partial,
                          int* __restrict__ out, int* __restrict__ cursor, int n) {
    __shared__ int red[256];
    int b = blockIdx.x, t = threadIdx.x;
    int base = b * 1024 + t * 4;
    int v[4];
    int s = 0;
#pragma unroll
    for (int k = 0; k < 4; ++k) {
        int j = base + k;
        v[k] = (j < n) ? in[j] : 0;
        s += v[k];
    }
    red[t] = s;
    __syncthreads();
    for (int off = 1; off < 256; off <<= 1) {
        int u = (t >= off) ? red[t - off] : 0;
        __syncthreads();
        red[t] += u;
        __syncthreads();
    }
    int tbase = partial[b] + red[t] - s;
#pragma unroll
    for (int k = 0; k < 4; ++k) {
        int j = base + k;
        if (j < n) {
            out[j] = tbase;
            if (cursor) cursor[j] = tbase;
            tbase += v[k];
        }
    }
}

// ---------------- browptr via binary search on sorted batch ----------------
__global__ void k_bsearch(const int* __restrict__ batch, int* __restrict__ browptr,
                          int nN, int nG) {
    int g = blockIdx.x * blockDim.x + threadIdx.x;
    if (g > nG) return;
    int lo = 0, hi = nN;
    while (lo < hi) {
        int mid = (lo + hi) >> 1;
        if (batch[mid] < g) lo = mid + 1; else hi = mid;
    }
    browptr[g] = lo;
}

// ---------------- scatter edges into dst-buckets ----------------
__global__ void k_scatter(const int* __restrict__ src, const int* __restrict__ dst,
                          int* __restrict__ cursor, int* __restrict__ eidx, int E) {
    int e = blockIdx.x * blockDim.x + threadIdx.x;
    if (e >= E) return;
    int slot = atomicAdd(&cursor[dst[e]], 1);
    eidx[slot] = src[e];
}

// ---------------- W repack: fp32 [128][128] -> bf16 B-fragment order ----------------
// wpk[((kb*8+c16)*64 + lane)*8 + j] = bf16( W[kb*32 + (lane>>4)*8 + j][c16*16 + (lane&15)] )
__global__ void k_wpack(const float* __restrict__ W, unsigned short* __restrict__ wpk) {
    int t = blockIdx.x * blockDim.x + threadIdx.x;
    if (t >= 2048) return;
    int lane = t & 63, fc = t >> 6;
    int kb = fc >> 3, c16 = fc & 7;
    int col = c16 * 16 + (lane & 15);
    int k0 = kb * 32 + (lane >> 4) * 8;
    unsigned r[4];
#pragma unroll
    for (int p = 0; p < 4; ++p) {
        float a = W[(size_t)(k0 + 2 * p) * H + col];
        float b = W[(size_t)(k0 + 2 * p + 1) * H + col];
        r[p] = f2bf2(a, b);
    }
    *(uint4*)(wpk + (size_t)t * 8) = make_uint4(r[0], r[1], r[2], r[3]);
}

// ---------------- gather-aggregate pos (C=2) ----------------
__global__ void k_gather_pos(const int* __restrict__ rowptr, const int* __restrict__ eidx,
                             const float* __restrict__ pos, float* __restrict__ agg, int nN) {
    int i = blockIdx.x * blockDim.x + threadIdx.x;
    if (i >= nN) return;
    int j0 = rowptr[i], j1 = rowptr[i + 1];
    float ax = 0.f, ay = 0.f;
    for (int j = j0; j < j1; ++j) {
        float2 p = ((const float2*)pos)[eidx[j]];
        ax += p.x; ay += p.y;
    }
    agg[i * 2 + 0] = ax;
    agg[i * 2 + 1] = ay;
}

// ---------------- gather + self-add on bf16 rows: out = bf16(x[i] + sum x[src]) ----------------
__global__ void k_gather_add(const int* __restrict__ rowptr, const int* __restrict__ eidx,
                             const unsigned short* __restrict__ x, unsigned short* __restrict__ out,
                             int nN) {
    int idx = blockIdx.x * blockDim.x + threadIdx.x;
    int i = idx >> 4, q = idx & 15;  // q: 8-elem chunk
    if (i >= nN) return;
    const int off = q * 8;
    float a[8] = {0, 0, 0, 0, 0, 0, 0, 0};
    unpack_add8(*(const uint4*)(x + (size_t)i * H + off), a);
    int j0 = rowptr[i], j1 = rowptr[i + 1];
    for (int j = j0; j < j1; ++j) {
        int s = eidx[j];
        unpack_add8(*(const uint4*)(x + (size_t)s * H + off), a);
    }
    *(uint4*)(out + (size_t)i * H + off) =
        make_uint4(f2bf2(a[0], a[1]), f2bf2(a[2], a[3]), f2bf2(a[4], a[5]), f2bf2(a[6], a[7]));
}

// ---------------- segmented pool of bf16 features -> fp32 [G,H] ----------------
__global__ void k_pool_seg_bf(const unsigned short* __restrict__ x, const int* __restrict__ browptr,
                              float* __restrict__ pool) {
    int g = blockIdx.x, t = threadIdx.x;  // 128 threads
    int r0 = browptr[g], r1 = browptr[g + 1];
    float acc = 0.f;
    for (int r = r0; r < r1; ++r) acc += bf2f(x[(size_t)r * H + t]);
    pool[g * H + t] = acc;
}

__global__ void k_pool_pos_seg(const float* __restrict__ pos, const int* __restrict__ browptr,
                               float* __restrict__ pp) {
    int g = blockIdx.x, t = threadIdx.x;  // 64 threads
    int r0 = browptr[g], r1 = browptr[g + 1];
    float ax = 0.f, ay = 0.f;
    for (int r = r0 + t; r < r1; r += 64) {
        float2 p = ((const float2*)pos)[r];
        ax += p.x; ay += p.y;
    }
    for (int off = 32; off; off >>= 1) {
        ax += __shfl_down(ax, off);
        ay += __shfl_down(ay, off);
    }
    if (t == 0) { pp[g * 2] = ax; pp[g * 2 + 1] = ay; }
}

// ---------------- first GIN1 linear: [N,2] -> [N,128] bf16, relu ----------------
__global__ void k_in2(const float* __restrict__ pos, const float* __restrict__ agg,
                      const float* __restrict__ W, const float* __restrict__ b,
                      unsigned short* __restrict__ out, int nN) {
    int idx = blockIdx.x * blockDim.x + threadIdx.x;
    int i = idx >> 5, q = idx & 31;
    if (i >= nN) return;
    float2 p = ((const float2*)pos)[i];
    float2 a = ((const float2*)agg)[i];
    float x0 = p.x + a.x, x1 = p.y + a.y;
    float4 w0 = ld4(&W[q * 4]);
    float4 w1 = ld4(&W[H + q * 4]);
    float4 bb = ld4(&b[q * 4]);
    float r0 = fmaxf(x0 * w0.x + x1 * w1.x + bb.x, 0.f);
    float r1 = fmaxf(x0 * w0.y + x1 * w1.y + bb.y, 0.f);
    float r2 = fmaxf(x0 * w0.z + x1 * w1.z + bb.z, 0.f);
    float r3 = fmaxf(x0 * w0.w + x1 * w1.w + bb.w, 0.f);
    *(uint2*)(out + (size_t)i * H + q * 4) = make_uint2(f2bf2(r0, r1), f2bf2(r2, r3));
}

// ---------------- MFMA matmul: out_bf16 = [BN](relu(x_bf16 @ W + b)) ----------------
// D = mfma(Wfrag, xfrag): lane holds row = rowbase + rr*16 + (lane&15),
// cols = c16*16 + (lane>>4)*4 + {0..3}  -> packed row-major bf16 stores.
template <bool HAS_BN>
__global__ __launch_bounds__(256) void k_mm_mfma(
    const unsigned short* __restrict__ xin, const unsigned short* __restrict__ wpk,
    const float* __restrict__ bias,
    const float* __restrict__ bn_g, const float* __restrict__ bn_b,
    const float* __restrict__ bn_rm, const float* __restrict__ bn_rv,
    unsigned short* __restrict__ out, int nN) {
    __shared__ unsigned short Wl[H * H];  // 32 KB bf16
    __shared__ float sB[H], sS[H], sH[H];
    const int t = threadIdx.x;

    {   // stage packed W
        const uint4* s = (const uint4*)wpk;
        uint4* d = (uint4*)Wl;
#pragma unroll
        for (int r = 0; r < 8; ++r) d[r * 256 + t] = s[r * 256 + t];
    }
    if (t < H) {
        sB[t] = bias[t];
        if (HAS_BN) {
            float s = bn_g[t] * rsqrtf(bn_rv[t] + 1e-5f);
            sS[t] = s;
            sH[t] = bn_b[t] - bn_rm[t] * s;
        }
    }
    __syncthreads();

    const int lane = t & 63;
    const int wave = t >> 6;
    const int rowbase = blockIdx.x * 128 + wave * 32;
    const int lrow = lane & 15;
    const int lhi = lane >> 4;

    f32x4 acc[2][8];
#pragma unroll
    for (int rr = 0; rr < 2; ++rr)
#pragma unroll
        for (int c = 0; c < 8; ++c) acc[rr][c] = (f32x4){0.f, 0.f, 0.f, 0.f};

    const short8v* Wv = (const short8v*)Wl;

#pragma unroll
    for (int kb = 0; kb < 4; ++kb) {
        short8v xf[2];
#pragma unroll
        for (int rr = 0; rr < 2; ++rr) {
            int row = rowbase + rr * 16 + lrow;
            row = row < nN ? row : nN - 1;
            xf[rr] = *(const short8v*)(xin + (size_t)row * H + kb * 32 + lhi * 8);
        }
#pragma unroll
        for (int c16 = 0; c16 < 8; ++c16) {
            short8v wf = Wv[(kb * 8 + c16) * 64 + lane];
            acc[0][c16] = __builtin_amdgcn_mfma_f32_16x16x32_bf16(wf, xf[0], acc[0][c16], 0, 0, 0);
            acc[1][c16] = __builtin_amdgcn_mfma_f32_16x16x32_bf16(wf, xf[1], acc[1][c16], 0, 0, 0);
        }
    }

    // epilogue: +bias, relu, [BN], pack bf16
#pragma unroll
    for (int c16 = 0; c16 < 8; ++c16) {
        const int c0 = c16 * 16 + lhi * 4;
        float b0 = sB[c0], b1 = sB[c0 + 1], b2 = sB[c0 + 2], b3 = sB[c0 + 3];
        float s0, s1, s2, s3, h0, h1, h2, h3;
        if (HAS_BN) {
            s0 = sS[c0]; s1 = sS[c0 + 1]; s2 = sS[c0 + 2]; s3 = sS[c0 + 3];
            h0 = sH[c0]; h1 = sH[c0 + 1]; h2 = sH[c0 + 2]; h3 = sH[c0 + 3];
        }
#pragma unroll
        for (int rr = 0; rr < 2; ++rr) {
            int row = rowbase + rr * 16 + lrow;
            if (row >= nN) continue;
            float v0 = fmaxf(acc[rr][c16][0] + b0, 0.f);
            float v1 = fmaxf(acc[rr][c16][1] + b1, 0.f);
            float v2 = fmaxf(acc[rr][c16][2] + b2, 0.f);
            float v3 = fmaxf(acc[rr][c16][3] + b3, 0.f);
            if (HAS_BN) {
                v0 = v0 * s0 + h0; v1 = v1 * s1 + h1;
                v2 = v2 * s2 + h2; v3 = v3 * s3 + h3;
            }
            *(uint2*)(out + (size_t)row * H + c0) = make_uint2(f2bf2(v0, v1), f2bf2(v2, v3));
        }
    }
}

// ---------------- graph-level fc (fp32) ----------------
__global__ void k_fc_graph(const float* __restrict__ a, const float* __restrict__ b2,
                           const float* __restrict__ c3,
                           const float* __restrict__ W, const float* __restrict__ bias,
                           const float* __restrict__ g, const float* __restrict__ be,
                           const float* __restrict__ rm, const float* __restrict__ rv,
                           float* __restrict__ out, int K) {
    __shared__ float row[H];
    int gi = blockIdx.x, k = threadIdx.x;
    if (k < K) {
        float v = a[gi * K + k];
        if (b2) v += b2[gi * K + k];
        if (c3) v += c3[gi * K + k];
        row[k] = v;
    }
    __syncthreads();
    float acc = bias[k];
    for (int j = 0; j < K; ++j) acc += row[j] * W[j * H + k];
    acc = fmaxf(acc, 0.f);
    float s = g[k] * rsqrtf(rv[k] + 1e-5f);
    out[gi * H + k] = (acc - rm[k]) * s + be[k];
}

// ---------------- classifier head (fp32) ----------------
__global__ void k_cls(const float* __restrict__ x2g,
                      const float* __restrict__ Wc1, const float* __restrict__ bc1,
                      const float* __restrict__ gc, const float* __restrict__ bec,
                      const float* __restrict__ rmc, const float* __restrict__ rvc,
                      const float* __restrict__ a_prelu,
                      const float* __restrict__ Wc2, const float* __restrict__ bc2,
                      float* __restrict__ out) {
    __shared__ float row[H];
    __shared__ float hbuf[HC];
    int gi = blockIdx.x, t = threadIdx.x;
    row[t] = x2g[gi * H + t];
    __syncthreads();
    if (t < HC) {
        float acc = bc1[t];
        for (int j = 0; j < H; ++j) acc += row[j] * Wc1[j * HC + t];
        float s = gc[t] * rsqrtf(rvc[t] + 1e-5f);
        acc = (acc - rmc[t]) * s + bec[t];
        float a = a_prelu[0];
        hbuf[t] = acc > 0.f ? acc : a * acc;
    }
    __syncthreads();
    if (t < NOUT) {
        float acc = bc2[t];
        for (int j = 0; j < HC; ++j) acc += hbuf[j] * Wc2[j * NOUT + t];
        out[gi * NOUT + t] = acc;
    }
}

extern "C" void kernel_launch(void* const* d_in, const int* in_sizes, int n_in,
                              void* d_out, int out_size, void* d_ws, size_t ws_size,
                              hipStream_t stream) {
    const int N = kN, E = kE, G = kG;
    const float* pos = (const float*)d_in[0];
    const int* ei    = (const int*)d_in[1];
    const int* batch = (const int*)d_in[2];
    const float* W1a = (const float*)d_in[3];
    const float* b1a = (const float*)d_in[4];
    const float* W1b = (const float*)d_in[5];
    const float* b1b = (const float*)d_in[6];
    const float* n1g = (const float*)d_in[7];
    const float* n1b = (const float*)d_in[8];
    const float* n1rm = (const float*)d_in[9];
    const float* n1rv = (const float*)d_in[10];
    const float* W2a = (const float*)d_in[11];
    const float* b2a = (const float*)d_in[12];
    const float* W2b = (const float*)d_in[13];
    const float* b2b = (const float*)d_in[14];
    const float* n2g = (const float*)d_in[15];
    const float* n2b = (const float*)d_in[16];
    const float* n2rm = (const float*)d_in[17];
    const float* n2rv = (const float*)d_in[18];
    const float* Wf1 = (const float*)d_in[19];
    const float* bf1 = (const float*)d_in[20];
    const float* f1g = (const float*)d_in[21];
    const float* f1b = (const float*)d_in[22];
    const float* f1rm = (const float*)d_in[23];
    const float* f1rv = (const float*)d_in[24];
    const float* Wf2 = (const float*)d_in[25];
    const float* bf2 = (const float*)d_in[26];
    const float* f2g = (const float*)d_in[27];
    const float* f2b = (const float*)d_in[28];
    const float* f2rm = (const float*)d_in[29];
    const float* f2rv = (const float*)d_in[30];
    const float* Wc1 = (const float*)d_in[31];
    const float* bc1 = (const float*)d_in[32];
    const float* gc  = (const float*)d_in[33];
    const float* bec = (const float*)d_in[34];
    const float* rmc = (const float*)d_in[35];
    const float* rvc = (const float*)d_in[36];
    const float* ap  = (const float*)d_in[37];
    const float* Wc2 = (const float*)d_in[38];
    const float* bc2 = (const float*)d_in[39];
    float* out = (float*)d_out;

    // ---- workspace layout ----
    unsigned short* bh1 = (unsigned short*)d_ws;        // N*H bf16 (hA1 / s2 / x2)
    unsigned short* bx1 = bh1 + (size_t)N * H;          // N*H bf16 (x1 / hA2)
    unsigned short* wp1 = bx1 + (size_t)N * H;          // 16384
    unsigned short* wp2 = wp1 + 16384;
    unsigned short* wp3 = wp2 + 16384;
    float* aggp  = (float*)(wp3 + 16384);               // N*2
    float* ppool = aggp + (size_t)N * 2;                // G*2
    float* pool1 = ppool + (size_t)G * 2;               // G*H
    float* pool2 = pool1 + (size_t)G * H;               // G*H
    float* x0g   = pool2 + (size_t)G * H;               // G*H
    float* x1g   = x0g + (size_t)G * H;                 // G*H
    float* x2g   = x1g + (size_t)G * H;                 // G*H
    int* deg     = (int*)(x2g + (size_t)G * H);         // N (reused as cursor)
    int* rowptr  = deg + N;                             // N+1
    int* browptr = rowptr + N + 1;                      // G+1
    int* partial = browptr + G + 1;                     // 1024
    int* eidx    = partial + 1024;                      // E

    const int* src  = ei;
    const int* dstp = ei + E;
    const int nb = (N + 1023) / 1024;

    // ---- CSR build (by dst) + batch boundaries + W repack ----
    hipMemsetAsync(deg, 0, (size_t)N * sizeof(int), stream);
    k_wpack<<<8, 256, 0, stream>>>(W1b, wp1);
    k_wpack<<<8, 256, 0, stream>>>(W2a, wp2);
    k_wpack<<<8, 256, 0, stream>>>(W2b, wp3);
    k_hist<<<(E + 255) / 256, 256, 0, stream>>>(dstp, deg, E);
    k_bsearch<<<(G + 256) / 256, 256, 0, stream>>>(batch, browptr, N, G);
    k_scan_p1<<<nb, 256, 0, stream>>>(deg, partial, N);
    k_scan_p2<<<1, 1024, 0, stream>>>(partial, rowptr + N, nb);
    k_scan_p3<<<nb, 256, 0, stream>>>(deg, partial, rowptr, deg, N);
    k_scatter<<<(E + 255) / 256, 256, 0, stream>>>(src, dstp, deg, eidx, E);

    // ---- graph-level pos pooling + x0_g ----
    k_gather_pos<<<(N + 255) / 256, 256, 0, stream>>>(rowptr, eidx, pos, aggp, N);
    k_pool_pos_seg<<<G, 64, 0, stream>>>(pos, browptr, ppool);
    k_fc_graph<<<G, H, 0, stream>>>(ppool, nullptr, nullptr, Wf1, bf1, f1g, f1b, f1rm, f1rv, x0g, 2);

    const int mmBlocks = (N + 127) / 128;

    // ---- GIN1: hA1 -> x1 ----
    k_in2<<<(N * 32 + 255) / 256, 256, 0, stream>>>(pos, aggp, W1a, b1a, bh1, N);
    k_mm_mfma<true><<<mmBlocks, 256, 0, stream>>>(bh1, wp1, b1b, n1g, n1b, n1rm, n1rv, bx1, N);

    // s2 = bf16(x1 + gather(x1)) -> bh1 ; pool1 ; x1_g
    k_gather_add<<<(N * 16 + 255) / 256, 256, 0, stream>>>(rowptr, eidx, bx1, bh1, N);
    k_pool_seg_bf<<<G, H, 0, stream>>>(bx1, browptr, pool1);
    k_fc_graph<<<G, H, 0, stream>>>(x0g, pool1, nullptr, Wf2, bf2, f2g, f2b, f2rm, f2rv, x1g, H);

    // ---- GIN2: hA2 = relu(s2@W2a+b2a) -> bx1 ; x2 = BN(relu(hA2@W2b+b2b)) -> bh1 ----
    k_mm_mfma<false><<<mmBlocks, 256, 0, stream>>>(bh1, wp2, b2a, nullptr, nullptr, nullptr, nullptr, bx1, N);
    k_mm_mfma<true><<<mmBlocks, 256, 0, stream>>>(bx1, wp3, b2b, n2g, n2b, n2rm, n2rv, bh1, N);
    k_pool_seg_bf<<<G, H, 0, stream>>>(bh1, browptr, pool2);
    k_fc_graph<<<G, H, 0, stream>>>(x0g, x1g, pool2, Wf2, bf2, f2g, f2b, f2rm, f2rv, x2g, H);

    // ---- classifier ----
    k_cls<<<G, H, 0, stream>>>(x2g, Wc1, bc1, gc, bec, rmc, rvc, ap, Wc2, bc2, out);
}